// Round 3
// baseline (581.955 us; speedup 1.0000x reference)
//
#include <hip/hip_runtime.h>

#define D_DIM 2048
#define E_NUM 64
#define M_TOK 16384          // B*L = 4*4096
#define BM 64

// ws layout: part [nsplit][M_TOK][E_NUM] f32, then blockp[64][64], blockc[64][64]

// ---------------- GEMM: no LDS, stream x/W from global, 4x4 frag ----------------
// 256 thr: ty=tid>>4 (16 token-quads), tx=tid&15 (16 expert-quads).
// NOTE: no min-wave launch_bounds — R2's (256,4) forced VGPR=64 and spilled
// (WRITE_SIZE 231MB of scratch traffic). Accumulator tile needs ~122 VGPRs.
__global__ __launch_bounds__(256) void gemm_kernel(
    const float* __restrict__ x, const float* __restrict__ W,
    float* __restrict__ part, int ksplit)
{
    const int tid = threadIdx.x;
    const int tx  = tid & 15;
    const int ty  = tid >> 4;
    const long tokbase = (long)blockIdx.x * BM;
    const int  kbase   = blockIdx.y * ksplit;

    const float* xp[4];
    const float* wp[4];
    #pragma unroll
    for (int i = 0; i < 4; ++i) {
        xp[i] = x + (tokbase + (long)(ty * 4 + i)) * D_DIM + kbase;
        wp[i] = W + (long)(tx * 4 + i) * D_DIM + kbase;
    }

    double accd[4][4];
    #pragma unroll
    for (int i = 0; i < 4; ++i)
        #pragma unroll
        for (int j = 0; j < 4; ++j) accd[i][j] = 0.0;

    for (int kc = 0; kc < ksplit; kc += 32) {
        // packed-pair fp32 accumulators (lo/hi lanes of v_pk_fma_f32)
        float2 acc2[4][4];
        #pragma unroll
        for (int i = 0; i < 4; ++i)
            #pragma unroll
            for (int j = 0; j < 4; ++j) { acc2[i][j].x = 0.0f; acc2[i][j].y = 0.0f; }

        #pragma unroll
        for (int kb = 0; kb < 8; ++kb) {
            const int ko = kc + kb * 4;
            float4 xv[4], wv[4];
            #pragma unroll
            for (int i = 0; i < 4; ++i) xv[i] = *(const float4*)(xp[i] + ko);
            #pragma unroll
            for (int j = 0; j < 4; ++j) wv[j] = *(const float4*)(wp[j] + ko);
            #pragma unroll
            for (int i = 0; i < 4; ++i)
                #pragma unroll
                for (int j = 0; j < 4; ++j) {
                    acc2[i][j].x += xv[i].x * wv[j].x;
                    acc2[i][j].y += xv[i].y * wv[j].y;
                    acc2[i][j].x += xv[i].z * wv[j].z;
                    acc2[i][j].y += xv[i].w * wv[j].w;
                }
        }
        // fold fp32 chunk -> fp64 every 32 k (keeps index-exact accuracy)
        #pragma unroll
        for (int i = 0; i < 4; ++i)
            #pragma unroll
            for (int j = 0; j < 4; ++j)
                accd[i][j] += (double)acc2[i][j].x + (double)acc2[i][j].y;
    }

    float* dst = part + (size_t)blockIdx.y * ((size_t)M_TOK * E_NUM);
    #pragma unroll
    for (int i = 0; i < 4; ++i) {
        const long m = tokbase + ty * 4 + i;
        float4 v;
        v.x = (float)accd[i][0]; v.y = (float)accd[i][1];
        v.z = (float)accd[i][2]; v.w = (float)accd[i][3];
        *(float4*)&dst[m * E_NUM + (tx << 2)] = v;
    }
}

// ---------------- top-k: thread-per-token, 256 tokens/block ----------------
#define RS 68   // LDS row stride (float4-aligned, coprime-ish banks)
__global__ __launch_bounds__(256) void topk_kernel(
    const float* __restrict__ part, float* __restrict__ out,
    float* __restrict__ blockp, float* __restrict__ blockc, int nsplit)
{
    __shared__ float red[256 * RS];       // 68 KB: per-token softmax probs
    __shared__ int   i1s[256];
    __shared__ float ppart[4 * 64];
    __shared__ float cpart[4 * 64];

    const int  tid = threadIdx.x;
    const long t   = (long)blockIdx.x * 256 + tid;

    float l[64];
    #pragma unroll
    for (int j = 0; j < 16; ++j) {
        const float4 v = *(const float4*)&part[t * E_NUM + j * 4];
        l[j * 4 + 0] = v.x; l[j * 4 + 1] = v.y; l[j * 4 + 2] = v.z; l[j * 4 + 3] = v.w;
    }
    for (int s = 1; s < nsplit; ++s) {
        #pragma unroll
        for (int j = 0; j < 16; ++j) {
            const float4 v = *(const float4*)&part[((size_t)s * M_TOK + t) * E_NUM + j * 4];
            l[j * 4 + 0] += v.x; l[j * 4 + 1] += v.y; l[j * 4 + 2] += v.z; l[j * 4 + 3] += v.w;
        }
    }

    // top-2, lowest-index tie-break (strict >, ascending scan) — matches lax.top_k
    float m1 = -1e30f, m2 = -1e30f; int i1 = 0, i2 = 0;
    #pragma unroll
    for (int e = 0; e < 64; ++e) {
        const float v = l[e];
        if (v > m1)      { m2 = m1; i2 = i1; m1 = v; i1 = e; }
        else if (v > m2) { m2 = v;  i2 = e; }
    }

    // full softmax (aux loss)
    float ssum = 0.0f;
    #pragma unroll
    for (int e = 0; e < 64; ++e) { l[e] = __expf(l[e] - m1); ssum += l[e]; }
    const float inv = 1.0f / ssum;
    #pragma unroll
    for (int j = 0; j < 16; ++j) {
        float4 v;
        v.x = l[j * 4 + 0] * inv; v.y = l[j * 4 + 1] * inv;
        v.z = l[j * 4 + 2] * inv; v.w = l[j * 4 + 3] * inv;
        *(float4*)&red[tid * RS + j * 4] = v;
    }
    i1s[tid] = i1;

    // per-token outputs
    float2 oi; oi.x = (float)i1; oi.y = (float)i2;
    *(float2*)&out[2 * t] = oi;
    const float w1 = 1.0f / (1.0f + __expf(m2 - m1));
    float2 ow; ow.x = w1; ow.y = 1.0f - w1;
    *(float2*)&out[2 * M_TOK + 2 * t] = ow;

    __syncthreads();
    // column reduction: thread (q,e) sums 64 tokens for expert e
    {
        const int q = tid >> 6, e = tid & 63;
        float P = 0.0f, C = 0.0f;
        #pragma unroll
        for (int u = 0; u < 64; ++u) {
            P += red[(q * 64 + u) * RS + e];
            C += (i1s[q * 64 + u] == e) ? 1.0f : 0.0f;
        }
        ppart[q * 64 + e] = P;
        cpart[q * 64 + e] = C;
    }
    __syncthreads();
    if (tid < 64) {
        blockp[blockIdx.x * E_NUM + tid] =
            ppart[tid] + ppart[64 + tid] + ppart[128 + tid] + ppart[192 + tid];
        blockc[blockIdx.x * E_NUM + tid] =
            cpart[tid] + cpart[64 + tid] + cpart[128 + tid] + cpart[192 + tid];
    }
}

// ---------------- aux reduction: one 256-thread block, parallel partials ----------------
__global__ __launch_bounds__(256) void aux_kernel(
    const float* __restrict__ blockp, const float* __restrict__ blockc,
    float* __restrict__ out)
{
    __shared__ float ppart[4 * 64];
    __shared__ float cpart[4 * 64];
    const int tid = threadIdx.x;
    const int q = tid >> 6, e = tid & 63;
    float P = 0.0f, C = 0.0f;
    #pragma unroll
    for (int b = 0; b < 16; ++b) {
        P += blockp[(q * 16 + b) * E_NUM + e];
        C += blockc[(q * 16 + b) * E_NUM + e];
    }
    ppart[q * 64 + e] = P;
    cpart[q * 64 + e] = C;
    __syncthreads();
    if (tid < 64) {
        const float Pt = ppart[tid] + ppart[64 + tid] + ppart[128 + tid] + ppart[192 + tid];
        const float Ct = cpart[tid] + cpart[64 + tid] + cpart[128 + tid] + cpart[192 + tid];
        float v = Pt * Ct;
        #pragma unroll
        for (int off = 32; off > 0; off >>= 1) v += __shfl_xor(v, off, 64);
        if (tid == 0)
            out[4 * M_TOK] = 64.0f * 0.01f * v / ((float)M_TOK * (float)M_TOK);
    }
}

extern "C" void kernel_launch(void* const* d_in, const int* in_sizes, int n_in,
                              void* d_out, int out_size, void* d_ws, size_t ws_size,
                              hipStream_t stream)
{
    const float* x = (const float*)d_in[0];
    const float* W = (const float*)d_in[1];
    float* out = (float*)d_out;

    const size_t need4 = (size_t)4 * M_TOK * E_NUM * sizeof(float)
                       + (size_t)2 * 64 * E_NUM * sizeof(float);
    const int nsplit = (ws_size >= need4) ? 4 : 2;   // ws-size constant across calls
    const int ksplit = D_DIM / nsplit;

    float* part   = (float*)d_ws;
    float* blockp = part + (size_t)nsplit * M_TOK * E_NUM;
    float* blockc = blockp + 64 * E_NUM;

    gemm_kernel<<<dim3(M_TOK / BM, nsplit), 256, 0, stream>>>(x, W, part, ksplit);
    topk_kernel<<<64, 256, 0, stream>>>(part, out, blockp, blockc, nsplit);
    aux_kernel<<<1, 256, 0, stream>>>(blockp, blockc, out);
}

// Round 4
// 278.812 us; speedup vs baseline: 2.0873x; 2.0873x over previous
//
#include <hip/hip_runtime.h>

#define D_DIM 2048
#define E_NUM 64
#define M_TOK 16384          // B*L = 4*4096
#define BMT 256              // tokens per gemm block
#define TILE_K 32
#define XS_S 36              // 32 + 4 pad; stride*9 -> bank-quad = (row + kq) mod 8
#define TPB 32               // tokens per topk block
#define NTB (M_TOK / TPB)    // 512 topk blocks

// ws layout: part [nsplit][M_TOK][E_NUM] f32, then blockp[NTB][64], blockc[NTB][64]

// ---------------- GEMM: LDS-tiled, 8x8 strided register tile ----------------
// Fragments strided (tokens ty+32i, experts tx+8j): each b128 LDS read hits 8
// distinct bank-quads (broadcast-only, no beyond-floor conflicts).
// fp32 accumulation per k-split (<=128 k): err ~2e-7 << min top-2 gap.
__global__ __launch_bounds__(256) void gemm_kernel(
    const float* __restrict__ x, const float* __restrict__ W,
    float* __restrict__ part, int ksplit)
{
    __shared__ float xs[BMT * XS_S];    // [token][k] natural
    __shared__ float wl[E_NUM * XS_S];  // [expert][k] natural

    const int tid = threadIdx.x;
    const int u  = tid & 7;          // staging k-quad
    const int v  = tid >> 3;         // staging row 0..31
    const int tx = tid & 7;          // expert lane: experts tx + 8j
    const int ty = tid >> 3;         // token lane: tokens ty + 32i
    const long tokbase = (long)blockIdx.x * BMT;
    const int  kbase   = blockIdx.y * ksplit;

    float acc[8][8];
    #pragma unroll
    for (int i = 0; i < 8; ++i)
        #pragma unroll
        for (int j = 0; j < 8; ++j) acc[i][j] = 0.0f;

    for (int t0 = 0; t0 < ksplit; t0 += TILE_K) {
        const int k0 = kbase + t0;
        // stage x: 256 rows x 32 k, coalesced b128 global, b128 LDS writes at BW floor
        #pragma unroll
        for (int p = 0; p < 8; ++p) {
            const int r = v + 32 * p;
            const float4 xv = *(const float4*)&x[(tokbase + r) * D_DIM + k0 + 4 * u];
            *(float4*)&xs[r * XS_S + 4 * u] = xv;
        }
        // stage W: 64 rows x 32 k
        #pragma unroll
        for (int q = 0; q < 2; ++q) {
            const int e = v + 32 * q;
            const float4 wv = *(const float4*)&W[(long)e * D_DIM + k0 + 4 * u];
            *(float4*)&wl[e * XS_S + 4 * u] = wv;
        }
        __syncthreads();
        #pragma unroll
        for (int kq = 0; kq < 8; ++kq) {
            float4 xv[8], wv[8];
            #pragma unroll
            for (int i = 0; i < 8; ++i)
                xv[i] = *(const float4*)&xs[(ty + 32 * i) * XS_S + 4 * kq];
            #pragma unroll
            for (int j = 0; j < 8; ++j)
                wv[j] = *(const float4*)&wl[(tx + 8 * j) * XS_S + 4 * kq];
            #pragma unroll
            for (int i = 0; i < 8; ++i)
                #pragma unroll
                for (int j = 0; j < 8; ++j) {
                    acc[i][j] += xv[i].x * wv[j].x;
                    acc[i][j] += xv[i].y * wv[j].y;
                    acc[i][j] += xv[i].z * wv[j].z;
                    acc[i][j] += xv[i].w * wv[j].w;
                }
        }
        __syncthreads();
    }
    // scatter-store partials (strided experts): 8x 32B segments per inst, ~0.4% of insts
    float* dst = part + (size_t)blockIdx.y * ((size_t)M_TOK * E_NUM);
    #pragma unroll
    for (int i = 0; i < 8; ++i) {
        const long m = tokbase + ty + 32 * i;
        #pragma unroll
        for (int j = 0; j < 8; ++j)
            dst[m * E_NUM + tx + 8 * j] = acc[i][j];
    }
}

// ---------------- top-k: 32 tokens/block, 8 scanners/token ----------------
__global__ __launch_bounds__(256) void topk_kernel(
    const float* __restrict__ part, float* __restrict__ out,
    float* __restrict__ blockp, float* __restrict__ blockc, int nsplit)
{
    __shared__ float ls[TPB][68];        // logits, then probs
    __shared__ float cand[TPB][8][4];    // per-scanner m1,i1,m2,i2
    __shared__ float esum[TPB][8];
    __shared__ float m1s[TPB];
    __shared__ int   i1s[TPB];
    __shared__ float invs[TPB];
    __shared__ float ppart[4][64];
    __shared__ float cpart[4][64];

    const int tid = threadIdx.x;
    const size_t base = (size_t)blockIdx.x * TPB * E_NUM;   // dword offset

    // sum splits, coalesced: 2048 dwords/block, 2 float4 per thread
    float4 a0, a1;
    a0.x = a0.y = a0.z = a0.w = 0.0f;
    a1.x = a1.y = a1.z = a1.w = 0.0f;
    for (int s = 0; s < nsplit; ++s) {
        const float* sp = part + (size_t)s * ((size_t)M_TOK * E_NUM) + base;
        const float4 v0 = *(const float4*)&sp[tid * 4];
        const float4 v1 = *(const float4*)&sp[tid * 4 + 1024];
        a0.x += v0.x; a0.y += v0.y; a0.z += v0.z; a0.w += v0.w;
        a1.x += v1.x; a1.y += v1.y; a1.z += v1.z; a1.w += v1.w;
    }
    {
        const int off0 = tid * 4;
        *(float4*)&ls[off0 >> 6][off0 & 63] = a0;
        const int off1 = tid * 4 + 1024;
        *(float4*)&ls[off1 >> 6][off1 & 63] = a1;
    }
    __syncthreads();

    const int tok = tid >> 3, q = tid & 7;
    // local top-2 over experts 8q..8q+7 (total order: value desc, index asc)
    {
        float m1 = -1e30f, m2 = -1e30f; int i1 = -1, i2 = -1;
        #pragma unroll
        for (int n = 0; n < 8; ++n) {
            const int e = 8 * q + n;
            const float vv = ls[tok][e];
            if (vv > m1) { m2 = m1; i2 = i1; m1 = vv; i1 = e; }
            else if (vv > m2) { m2 = vv; i2 = e; }
        }
        cand[tok][q][0] = m1; cand[tok][q][1] = (float)i1;
        cand[tok][q][2] = m2; cand[tok][q][3] = (float)i2;
    }
    __syncthreads();
    if (q == 0) {
        float m1 = -1e30f, m2 = -1e30f; int i1 = 1 << 20, i2 = 1 << 20;
        #pragma unroll
        for (int qq = 0; qq < 8; ++qq) {
            #pragma unroll
            for (int h = 0; h < 2; ++h) {
                const float vv = cand[tok][qq][2 * h];
                const int   ii = (int)cand[tok][qq][2 * h + 1];
                if (ii < 0) continue;
                if (vv > m1 || (vv == m1 && ii < i1)) { m2 = m1; i2 = i1; m1 = vv; i1 = ii; }
                else if (vv > m2 || (vv == m2 && ii < i2)) { m2 = vv; i2 = ii; }
            }
        }
        m1s[tok] = m1; i1s[tok] = i1;
        const long t = (long)blockIdx.x * TPB + tok;
        float2 oi; oi.x = (float)i1; oi.y = (float)i2;
        *(float2*)&out[2 * t] = oi;
        const float w1 = 1.0f / (1.0f + __expf(m2 - m1));
        float2 ow; ow.x = w1; ow.y = 1.0f - w1;
        *(float2*)&out[2 * M_TOK + 2 * t] = ow;
    }
    __syncthreads();
    // softmax partials
    {
        const float m1v = m1s[tok];
        float es = 0.0f;
        float ex[8];
        #pragma unroll
        for (int n = 0; n < 8; ++n) { ex[n] = __expf(ls[tok][8 * q + n] - m1v); es += ex[n]; }
        esum[tok][q] = es;
        __syncthreads();
        if (q == 0) {
            float s = 0.0f;
            #pragma unroll
            for (int qq = 0; qq < 8; ++qq) s += esum[tok][qq];
            invs[tok] = 1.0f / s;
        }
        __syncthreads();
        const float inv = invs[tok];
        #pragma unroll
        for (int n = 0; n < 8; ++n) ls[tok][8 * q + n] = ex[n] * inv;
    }
    __syncthreads();
    // per-expert column partials over the 32 tokens
    {
        const int e = tid & 63, g = tid >> 6;
        float P = 0.0f, C = 0.0f;
        #pragma unroll
        for (int uu = 0; uu < 8; ++uu) {
            const int tk = g * 8 + uu;
            P += ls[tk][e];
            C += (i1s[tk] == e) ? 1.0f : 0.0f;
        }
        ppart[g][e] = P; cpart[g][e] = C;
    }
    __syncthreads();
    if (tid < 64) {
        blockp[blockIdx.x * E_NUM + tid] =
            ppart[0][tid] + ppart[1][tid] + ppart[2][tid] + ppart[3][tid];
        blockc[blockIdx.x * E_NUM + tid] =
            cpart[0][tid] + cpart[1][tid] + cpart[2][tid] + cpart[3][tid];
    }
}

// ---------------- aux reduction ----------------
__global__ __launch_bounds__(256) void aux_kernel(
    const float* __restrict__ blockp, const float* __restrict__ blockc,
    float* __restrict__ out)
{
    __shared__ float ppart[4][64];
    __shared__ float cpart[4][64];
    const int tid = threadIdx.x;
    const int e = tid & 63, g = tid >> 6;
    float P = 0.0f, C = 0.0f;
    for (int b = 0; b < NTB / 4; ++b) {
        P += blockp[(g * (NTB / 4) + b) * E_NUM + e];
        C += blockc[(g * (NTB / 4) + b) * E_NUM + e];
    }
    ppart[g][e] = P; cpart[g][e] = C;
    __syncthreads();
    if (tid < 64) {
        const float Pt = ppart[0][tid] + ppart[1][tid] + ppart[2][tid] + ppart[3][tid];
        const float Ct = cpart[0][tid] + cpart[1][tid] + cpart[2][tid] + cpart[3][tid];
        float vv = Pt * Ct;
        #pragma unroll
        for (int off = 32; off > 0; off >>= 1) vv += __shfl_xor(vv, off, 64);
        if (tid == 0)
            out[4 * M_TOK] = 64.0f * 0.01f * vv / ((float)M_TOK * (float)M_TOK);
    }
}

extern "C" void kernel_launch(void* const* d_in, const int* in_sizes, int n_in,
                              void* d_out, int out_size, void* d_ws, size_t ws_size,
                              hipStream_t stream)
{
    const float* x = (const float*)d_in[0];
    const float* W = (const float*)d_in[1];
    float* out = (float*)d_out;

    const size_t tailsz = (size_t)2 * NTB * E_NUM * sizeof(float);
    const size_t persplit = (size_t)M_TOK * E_NUM * sizeof(float);
    int nsplit = 16;
    while (nsplit > 2 && (size_t)nsplit * persplit + tailsz > ws_size) nsplit >>= 1;
    const int ksplit = D_DIM / nsplit;

    float* part   = (float*)d_ws;
    float* blockp = part + (size_t)nsplit * M_TOK * E_NUM;
    float* blockc = blockp + NTB * E_NUM;

    gemm_kernel<<<dim3(M_TOK / BMT, nsplit), 256, 0, stream>>>(x, W, part, ksplit);
    topk_kernel<<<NTB, 256, 0, stream>>>(part, out, blockp, blockc, nsplit);
    aux_kernel<<<1, 256, 0, stream>>>(blockp, blockc, out);
}